// Round 4
// baseline (286.905 us; speedup 1.0000x reference)
//
#include <hip/hip_runtime.h>
#include <cfloat>

// Shapes: z_e [32,64,64,64] fp32, codebook [512,64] fp32.
// d_out (fp32, flat): z_q_st [8388608] ++ indices [131072] ++ loss [1].
constexpr int C_DIM    = 64;
constexpr int K_CODES  = 512;
constexpr int HW       = 4096;
constexpr int CHW      = C_DIM * HW;      // 262144
constexpr int NPTS     = 131072;
constexpr int ZQ_SIZE  = 8388608;
constexpr int IDX_OFF  = ZQ_SIZE;
constexpr int LOSS_OFF = ZQ_SIZE + NPTS;
constexpr int TILE     = 128;             // points per block
constexpr int XROW     = 80;              // LDS row stride in floats: 320 B,
                                          // 16B-aligned, (16t+c)%32 -> 2-way banks (free)

__global__ void vq_zero_loss(float* __restrict__ out) { out[LOSS_OFF] = 0.0f; }

// numpy pairwise_sum of 64 fp32 squares (8-accumulator scheme) — bit-exact
// vs np.sum(a*a, axis=1) for a 64-long row.
template <int STRIDE>
__device__ __forceinline__ float np_sumsq64(const float* __restrict__ a) {
    float r[8];
#pragma unroll
    for (int j = 0; j < 8; ++j) { const float v = a[j * STRIDE]; r[j] = __fmul_rn(v, v); }
#pragma unroll
    for (int i = 8; i < 64; i += 8)
#pragma unroll
        for (int j = 0; j < 8; ++j) {
            const float v = a[(i + j) * STRIDE];
            r[j] = __fadd_rn(r[j], __fmul_rn(v, v));
        }
    return __fadd_rn(
        __fadd_rn(__fadd_rn(r[0], r[1]), __fadd_rn(r[2], r[3])),
        __fadd_rn(__fadd_rn(r[4], r[5]), __fadd_rn(r[6], r[7])));
}

#define REP16(M) M(0) M(1) M(2) M(3) M(4) M(5) M(6) M(7) \
                 M(8) M(9) M(10) M(11) M(12) M(13) M(14) M(15)

__global__ __launch_bounds__(256, 2) void vq_main(const float* __restrict__ ze,
                                                  const float* __restrict__ cb,
                                                  float* __restrict__ out)
{
    __shared__ __align__(16) float xs[TILE * XROW];   // 40960 B point tile
    __shared__ float  As[TILE];                        // per-point ||x||^2 (numpy order)
    __shared__ uint2  part[TILE * 4];                  // per-wave argmin partials
    __shared__ int    bestk[TILE];
    __shared__ double lred[4];

    const int tid = threadIdx.x;
    const int w   = tid >> 6;
    const int n0  = blockIdx.x * TILE;                 // grid = NPTS/TILE = 1024
    const int b   = n0 >> 12;
    const int hw0 = n0 & (HW - 1);

    // ---- This thread's two codebook rows -> named float4 registers ----
    const int k0 = 2 * tid, k1 = 2 * tid + 1;          // lane order == code order
    const float4* cbv = (const float4*)cb;
#define DECL_EF(i) float4 E##i, F##i;
    REP16(DECL_EF)
#define LOAD_EF(i) E##i = cbv[k0 * 16 + (i)]; F##i = cbv[k1 * 16 + (i)];
    REP16(LOAD_EF)
#define PIN4(V) asm volatile("" : "+v"(V.x), "+v"(V.y), "+v"(V.z), "+v"(V.w));
#define PIN_EF(i) PIN4(E##i) PIN4(F##i)
    REP16(PIN_EF)

    // B_k for the two codes (numpy pairwise, from global bits — init-time only).
    const float B0 = np_sumsq64<1>(cb + k0 * C_DIM);
    const float B1 = np_sumsq64<1>(cb + k1 * C_DIM);

    // ---- Stage x tile into LDS (coalesced reads, 2-way-bank writes) ----
    {
        const int hw  = tid & 127;
        const int ch0 = tid >> 7;                      // 0 or 1
        for (int i = 0; i < 32; ++i) {
            const int c = ch0 + 2 * i;
            xs[hw * XROW + c] = ze[b * CHW + c * HW + hw0 + hw];
        }
    }
    __syncthreads();

    // ---- A_n per point (numpy pairwise), threads 0..127 ----
    if (tid < TILE) As[tid] = np_sumsq64<1>(xs + tid * XROW);
    __syncthreads();

    // ---- Main loop: stream point pairs; codes resident in E/F regs ----
    // Per (pt, code): single sequential fmaf chain over c=0..63 (bit-exact
    // sgemm replication); D = fmaf(-2, M, fl(A+B)) = fl(fl(A+B) - 2M).
    for (int p = 0; p < TILE; p += 2) {
        const float4* xr0 = (const float4*)(xs + p * XROW);        // uniform
        const float4* xr1 = (const float4*)(xs + (p + 1) * XROW);  // uniform
        float a00 = 0.f, a01 = 0.f, a10 = 0.f, a11 = 0.f;
#define KSTEP(i) { \
        const float4 u = xr0[i]; const float4 v = xr1[i]; \
        a00 = fmaf(u.x, E##i.x, a00); a00 = fmaf(u.y, E##i.y, a00); \
        a00 = fmaf(u.z, E##i.z, a00); a00 = fmaf(u.w, E##i.w, a00); \
        a01 = fmaf(u.x, F##i.x, a01); a01 = fmaf(u.y, F##i.y, a01); \
        a01 = fmaf(u.z, F##i.z, a01); a01 = fmaf(u.w, F##i.w, a01); \
        a10 = fmaf(v.x, E##i.x, a10); a10 = fmaf(v.y, E##i.y, a10); \
        a10 = fmaf(v.z, E##i.z, a10); a10 = fmaf(v.w, E##i.w, a10); \
        a11 = fmaf(v.x, F##i.x, a11); a11 = fmaf(v.y, F##i.y, a11); \
        a11 = fmaf(v.z, F##i.z, a11); a11 = fmaf(v.w, F##i.w, a11); }
        REP16(KSTEP)

        const float A0 = As[p], A1 = As[p + 1];
        const float D00 = fmaf(-2.f, a00, __fadd_rn(A0, B0));
        const float D01 = fmaf(-2.f, a01, __fadd_rn(A0, B1));
        const float D10 = fmaf(-2.f, a10, __fadd_rn(A1, B0));
        const float D11 = fmaf(-2.f, a11, __fadd_rn(A1, B1));

        // Wave argmin, first-occurrence ties (lane order == code order).
        {
            const int   sel = (D01 < D00) ? 1 : 0;     // tie -> lower code
            const float dl  = sel ? D01 : D00;
            float m = dl;
#pragma unroll
            for (int off = 1; off < 64; off <<= 1) m = fminf(m, __shfl_xor(m, off, 64));
            const unsigned long long eq = __ballot(dl == m);
            const unsigned long long sm = __ballot(sel != 0);
            const int L   = __ffsll(eq) - 1;           // lowest lane == lowest code
            const int idx = 128 * w + 2 * L + (int)((sm >> L) & 1ull);
            if ((tid & 63) == 0) part[p * 4 + w] = make_uint2(__float_as_uint(m), (unsigned)idx);
        }
        {
            const int   sel = (D11 < D10) ? 1 : 0;
            const float dl  = sel ? D11 : D10;
            float m = dl;
#pragma unroll
            for (int off = 1; off < 64; off <<= 1) m = fminf(m, __shfl_xor(m, off, 64));
            const unsigned long long eq = __ballot(dl == m);
            const unsigned long long sm = __ballot(sel != 0);
            const int L   = __ffsll(eq) - 1;
            const int idx = 128 * w + 2 * L + (int)((sm >> L) & 1ull);
            if ((tid & 63) == 0) part[(p + 1) * 4 + w] = make_uint2(__float_as_uint(m), (unsigned)idx);
        }
    }
    __syncthreads();

    // ---- Phase 2: combine 4 wave partials (ascending wave == ascending code,
    //      strict < keeps first occurrence); write indices output ----
    if (tid < TILE) {
        uint2 p0 = part[tid * 4 + 0];
        float bm = __uint_as_float(p0.x);
        int   bi = (int)p0.y;
#pragma unroll
        for (int ww = 1; ww < 4; ++ww) {
            uint2 pp = part[tid * 4 + ww];
            const float mm = __uint_as_float(pp.x);
            if (mm < bm) { bm = mm; bi = (int)pp.y; }
        }
        bestk[tid] = bi;
        out[IDX_OFF + n0 + tid] = (float)bi;
    }
    __syncthreads();

    // ---- Epilogue: z_q_st + loss (bit-exact ref formula) ----
    const int pt   = tid & 127;
    const int half = tid >> 7;
    const int bi   = bestk[pt];
    const float* erow = cb + bi * C_DIM;
    float* orow = out + b * CHW + hw0 + pt;
    double ls = 0.0;
    for (int cc = 0; cc < 32; ++cc) {
        const int   c  = 32 * half + cc;
        const float xv = xs[pt * XROW + c];
        const float evv = erow[c];
        const float d  = __fsub_rn(evv, xv);           // ref: z_q - z_e
        orow[c * HW] = __fadd_rn(xv, d);               // ref: z_e + (...)
        ls = fma((double)d, (double)d, ls);
    }

#pragma unroll
    for (int off = 32; off > 0; off >>= 1) ls += __shfl_xor(ls, off, 64);
    if ((tid & 63) == 0) lred[w] = ls;
    __syncthreads();
    if (tid == 0) {
        const double t = lred[0] + lred[1] + lred[2] + lred[3];
        atomicAdd(out + LOSS_OFF, (float)(t * (1.25 / (double)ZQ_SIZE)));
    }
}

extern "C" void kernel_launch(void* const* d_in, const int* in_sizes, int n_in,
                              void* d_out, int out_size, void* d_ws, size_t ws_size,
                              hipStream_t stream) {
    (void)in_sizes; (void)n_in; (void)d_ws; (void)ws_size; (void)out_size;
    const float* ze = (const float*)d_in[0];
    const float* cb = (const float*)d_in[1];
    float* out = (float*)d_out;

    vq_zero_loss<<<1, 1, 0, stream>>>(out);
    vq_main<<<NPTS / TILE, 256, 0, stream>>>(ze, cb, out);
}

// Round 5
// 184.013 us; speedup vs baseline: 1.5592x; 1.5592x over previous
//
#include <hip/hip_runtime.h>
#include <cfloat>

typedef __attribute__((ext_vector_type(8))) short short8;
typedef __attribute__((ext_vector_type(4))) float f32x4;

// Shapes: z_e [32,64,64,64] fp32, codebook [512,64] fp32.
// d_out (fp32 flat): z_q_st [8388608] ++ indices [131072] ++ loss [1].
constexpr int C_DIM    = 64;
constexpr int K_CODES  = 512;
constexpr int HW       = 4096;
constexpr int CHW      = C_DIM * HW;
constexpr int NPTS     = 131072;
constexpr int ZQ_SIZE  = 8388608;
constexpr int IDX_OFF  = ZQ_SIZE;
constexpr int LOSS_OFF = ZQ_SIZE + NPTS;
constexpr int TILE     = 128;     // points per block (2 waves x 64)
constexpr int EH_STRIDE = 72;     // ushorts per code row in LDS (144 B, 16B-aligned)
constexpr int CHUNK    = 128;     // codes staged per LDS chunk
constexpr size_t WS_NEED = (size_t)K_CODES * C_DIM * 2;  // bf16 codebook in ws

__global__ void vq_zero_loss(float* __restrict__ out) { out[LOSS_OFF] = 0.0f; }

__device__ __forceinline__ unsigned short f32_to_bf16_rne(float f) {
    unsigned u = __float_as_uint(f);
    unsigned r = u + 0x7fffu + ((u >> 16) & 1u);
    return (unsigned short)(r >> 16);
}

// numpy pairwise_sum of 64 fp32 squares (8-accumulator scheme) — bit-exact
// vs np.sum(a*a, axis=1) for a 64-long row.
template <int STRIDE>
__device__ __forceinline__ float np_sumsq64(const float* __restrict__ a) {
    float r[8];
#pragma unroll
    for (int j = 0; j < 8; ++j) { const float v = a[j * STRIDE]; r[j] = __fmul_rn(v, v); }
#pragma unroll
    for (int i = 8; i < 64; i += 8)
#pragma unroll
        for (int j = 0; j < 8; ++j) {
            const float v = a[(i + j) * STRIDE];
            r[j] = __fadd_rn(r[j], __fmul_rn(v, v));
        }
    return __fadd_rn(
        __fadd_rn(__fadd_rn(r[0], r[1]), __fadd_rn(r[2], r[3])),
        __fadd_rn(__fadd_rn(r[4], r[5]), __fadd_rn(r[6], r[7])));
}

// Precompute bf16(RNE) codebook into workspace (re-run every launch; ws is
// re-poisoned by the harness before each call).
__global__ void vq_prep(const float* __restrict__ cb, unsigned short* __restrict__ wsb) {
    const int i = blockIdx.x * 256 + threadIdx.x;   // grid covers 512*64
    wsb[i] = f32_to_bf16_rne(cb[i]);
}

__global__ __launch_bounds__(128, 3) void vq_mfma(const float* __restrict__ ze,
                                                  const float* __restrict__ cb,
                                                  float* __restrict__ out,
                                                  const unsigned short* __restrict__ wsb,
                                                  int use_ws)
{
    __shared__ unsigned short eh[CHUNK * EH_STRIDE];  // 18432 B bf16 code chunk
    __shared__ float  Bs[K_CODES];
    __shared__ float  As[TILE];
    __shared__ float  thr[TILE];
    __shared__ unsigned short cand[TILE * 16];
    __shared__ int    cnt[TILE];
    __shared__ double lred[2];

    const int tid  = threadIdx.x;        // 0..127
    const int lane = tid & 63, w = tid >> 6;
    const int quad = lane >> 4, l15 = lane & 15;
    const int n0   = blockIdx.x * TILE;
    const int b    = n0 >> 12, hw0 = n0 & (HW - 1);
    const float* zebase = ze + b * CHW + hw0;

    // ---- init: Bs (numpy pairwise), As (numpy pairwise), counters ----
    for (int k = tid; k < K_CODES; k += 128) Bs[k] = np_sumsq64<1>(cb + k * C_DIM);
    As[tid] = np_sumsq64<HW>(zebase + tid);
    cnt[tid] = 0;
    __syncthreads();

    // ---- A fragments (bf16 RNE of x), resident in VGPRs; A values per pt ----
    // a_frag layout: A[m=lane&15][k=quad*8+j]; our m = point, k = channel.
    short8 afr[4][2];
    float  A_pt[4][4];
#pragma unroll
    for (int rt = 0; rt < 4; ++rt) {
        const int pt = w * 64 + rt * 16 + l15;
#pragma unroll
        for (int kc = 0; kc < 2; ++kc) {
            union { unsigned short s[8]; short8 v; } u;
#pragma unroll
            for (int j = 0; j < 8; ++j) {
                const int c = kc * 32 + quad * 8 + j;
                u.s[j] = f32_to_bf16_rne(zebase[c * HW + pt]);
            }
            afr[rt][kc] = u.v;
        }
#pragma unroll
        for (int r = 0; r < 4; ++r) A_pt[rt][r] = As[w * 64 + rt * 16 + quad * 4 + r];
    }

    auto stage_chunk = [&](int ch) {
        if (use_ws) {
            const uint4* src = (const uint4*)(wsb + (size_t)(ch * CHUNK + tid) * C_DIM);
            uint4* dst = (uint4*)(eh + tid * EH_STRIDE);
#pragma unroll
            for (int i = 0; i < 8; ++i) dst[i] = src[i];
        } else {
            const float4* src = (const float4*)(cb + (size_t)(ch * CHUNK + tid) * C_DIM);
            uint4* dst = (uint4*)(eh + tid * EH_STRIDE);
#pragma unroll
            for (int i = 0; i < 8; ++i) {
                const float4 f0 = src[2 * i], f1 = src[2 * i + 1];
                uint4 o;
                o.x = (unsigned)f32_to_bf16_rne(f0.x) | ((unsigned)f32_to_bf16_rne(f0.y) << 16);
                o.y = (unsigned)f32_to_bf16_rne(f0.z) | ((unsigned)f32_to_bf16_rne(f0.w) << 16);
                o.z = (unsigned)f32_to_bf16_rne(f1.x) | ((unsigned)f32_to_bf16_rne(f1.y) << 16);
                o.w = (unsigned)f32_to_bf16_rne(f1.z) | ((unsigned)f32_to_bf16_rne(f1.w) << 16);
                dst[i] = o;
            }
        }
    };

    // ---- pass 1: streaming min of approx D over all 512 codes ----
    float runmin[4][4];
#pragma unroll
    for (int rt = 0; rt < 4; ++rt)
#pragma unroll
        for (int r = 0; r < 4; ++r) runmin[rt][r] = FLT_MAX;

    for (int ch = 0; ch < 4; ++ch) {
        __syncthreads();
        stage_chunk(ch);
        __syncthreads();
        for (int tile = 0; tile < 8; ++tile) {
            const int cl = tile * 16 + l15;     // b_frag: B[n=lane&15][k=quad*8+j]
            const short8 b0 = *(const short8*)(eh + cl * EH_STRIDE + quad * 8);
            const short8 b1 = *(const short8*)(eh + cl * EH_STRIDE + 32 + quad * 8);
            const float bsv = Bs[ch * CHUNK + cl];
#pragma unroll
            for (int rt = 0; rt < 4; ++rt) {
                f32x4 acc = {0.f, 0.f, 0.f, 0.f};
                acc = __builtin_amdgcn_mfma_f32_16x16x32_bf16(afr[rt][0], b0, acc, 0, 0, 0);
                acc = __builtin_amdgcn_mfma_f32_16x16x32_bf16(afr[rt][1], b1, acc, 0, 0, 0);
#pragma unroll
                for (int r = 0; r < 4; ++r) {
                    const float D = fmaf(-2.f, acc[r], __fadd_rn(A_pt[rt][r], bsv));
                    runmin[rt][r] = fminf(runmin[rt][r], D);
                }
            }
        }
    }

    // cross-lane (16 lanes of each quad share the same 4 pts) + threshold.
    // margin: rigorous |D~ - D_chain| <= 2*(8*sqrt(A)/512)*2^-8 + slop, x3 headroom.
#pragma unroll
    for (int rt = 0; rt < 4; ++rt)
#pragma unroll
        for (int r = 0; r < 4; ++r) {
            float v = runmin[rt][r];
#pragma unroll
            for (int m = 1; m < 16; m <<= 1) v = fminf(v, __shfl_xor(v, m, 64));
            runmin[rt][r] = v;
        }
    if (l15 == 0) {
#pragma unroll
        for (int rt = 0; rt < 4; ++rt)
#pragma unroll
            for (int r = 0; r < 4; ++r)
                thr[w * 64 + rt * 16 + quad * 4 + r] =
                    runmin[rt][r] + (4e-4f * sqrtf(A_pt[rt][r]) + 3e-4f);
    }
    __syncthreads();

    float thrR[4][4];
#pragma unroll
    for (int rt = 0; rt < 4; ++rt)
#pragma unroll
        for (int r = 0; r < 4; ++r) thrR[rt][r] = thr[w * 64 + rt * 16 + quad * 4 + r];

    // ---- pass 2: recompute D (bit-identical), collect candidates ----
    for (int ch = 0; ch < 4; ++ch) {
        __syncthreads();
        stage_chunk(ch);
        __syncthreads();
        for (int tile = 0; tile < 8; ++tile) {
            const int cl = tile * 16 + l15;
            const short8 b0 = *(const short8*)(eh + cl * EH_STRIDE + quad * 8);
            const short8 b1 = *(const short8*)(eh + cl * EH_STRIDE + 32 + quad * 8);
            const float bsv = Bs[ch * CHUNK + cl];
#pragma unroll
            for (int rt = 0; rt < 4; ++rt) {
                f32x4 acc = {0.f, 0.f, 0.f, 0.f};
                acc = __builtin_amdgcn_mfma_f32_16x16x32_bf16(afr[rt][0], b0, acc, 0, 0, 0);
                acc = __builtin_amdgcn_mfma_f32_16x16x32_bf16(afr[rt][1], b1, acc, 0, 0, 0);
#pragma unroll
                for (int r = 0; r < 4; ++r) {
                    const float D = fmaf(-2.f, acc[r], __fadd_rn(A_pt[rt][r], bsv));
                    if (D <= thrR[rt][r]) {
                        const int ptI = w * 64 + rt * 16 + quad * 4 + r;
                        const int p = atomicAdd(&cnt[ptI], 1);
                        if (p < 16) cand[ptI * 16 + p] = (unsigned short)(ch * CHUNK + cl);
                    }
                }
            }
        }
    }
    __syncthreads();

    // ---- exact rescore (bit-exact numpy/BLAS replication), one thread per pt ----
    const float Av = As[tid];
    const int c = cnt[tid];
    float bD = FLT_MAX;
    int   bK = K_CODES;
    if (c <= 16) {
        for (int i = 0; i < c; ++i) {
            const int k = cand[tid * 16 + i];
            const float* er = cb + k * C_DIM;
            float M = 0.f;
#pragma unroll
            for (int cc = 0; cc < 64; ++cc) M = fmaf(zebase[cc * HW + tid], er[cc], M);
            const float D = fmaf(-2.f, M, __fadd_rn(Av, Bs[k]));
            if (D < bD || (D == bD && k < bK)) { bD = D; bK = k; }
        }
    } else {  // overflow fallback: exact scan of all codes (ascending, strict <)
        for (int k = 0; k < K_CODES; ++k) {
            const float* er = cb + k * C_DIM;
            float M = 0.f;
#pragma unroll
            for (int cc = 0; cc < 64; ++cc) M = fmaf(zebase[cc * HW + tid], er[cc], M);
            const float D = fmaf(-2.f, M, __fadd_rn(Av, Bs[k]));
            if (D < bD) { bD = D; bK = k; }
        }
    }
    out[IDX_OFF + n0 + tid] = (float)bK;

    // ---- epilogue: z_q_st (ref formula bitwise) + loss ----
    const float* er = cb + bK * C_DIM;
    float* op = out + b * CHW + hw0 + tid;
    double ls = 0.0;
    for (int cc = 0; cc < 64; ++cc) {
        const float xv = zebase[cc * HW + tid];
        const float d  = __fsub_rn(er[cc], xv);
        op[cc * HW] = __fadd_rn(xv, d);
        ls = fma((double)d, (double)d, ls);
    }
#pragma unroll
    for (int off = 32; off > 0; off >>= 1) ls += __shfl_xor(ls, off, 64);
    if ((tid & 63) == 0) lred[w] = ls;
    __syncthreads();
    if (tid == 0)
        atomicAdd(out + LOSS_OFF, (float)((lred[0] + lred[1]) * (1.25 / (double)ZQ_SIZE)));
}

extern "C" void kernel_launch(void* const* d_in, const int* in_sizes, int n_in,
                              void* d_out, int out_size, void* d_ws, size_t ws_size,
                              hipStream_t stream) {
    (void)in_sizes; (void)n_in; (void)out_size;
    const float* ze = (const float*)d_in[0];
    const float* cb = (const float*)d_in[1];
    float* out = (float*)d_out;
    const int use_ws = (ws_size >= WS_NEED) ? 1 : 0;
    unsigned short* wsb = (unsigned short*)d_ws;

    vq_zero_loss<<<1, 1, 0, stream>>>(out);
    if (use_ws) vq_prep<<<(K_CODES * C_DIM) / 256, 256, 0, stream>>>(cb, wsb);
    vq_mfma<<<NPTS / TILE, 128, 0, stream>>>(ze, cb, out, wsb, use_ws);
}

// Round 6
// 138.733 us; speedup vs baseline: 2.0680x; 1.3264x over previous
//
#include <hip/hip_runtime.h>
#include <cfloat>

typedef __attribute__((ext_vector_type(8))) short short8;
typedef __attribute__((ext_vector_type(4))) float f32x4;

// Shapes: z_e [32,64,64,64] fp32, codebook [512,64] fp32.
// d_out (fp32 flat): z_q_st [8388608] ++ indices [131072] ++ loss [1].
constexpr int C_DIM    = 64;
constexpr int K_CODES  = 512;
constexpr int HW       = 4096;
constexpr int CHW      = 262144;
constexpr int NPTS     = 131072;
constexpr int ZQ_SIZE  = 8388608;
constexpr int IDX_OFF  = ZQ_SIZE;
constexpr int LOSS_OFF = ZQ_SIZE + NPTS;
constexpr int TILE     = 128;      // points per block
constexpr int EH_STRIDE = 72;      // ushorts per LDS code row (144 B, 16B-aligned)
constexpr int CHUNK    = 128;      // codes per staged LDS chunk
constexpr int NSLOT    = 16;       // candidate slots per point
constexpr size_t WS_BF16 = (size_t)K_CODES * C_DIM * 2;   // 65536 B
constexpr size_t WS_NEED = WS_BF16 + (size_t)K_CODES * 4; // + Bs 2048 B

__device__ __forceinline__ unsigned short f32_to_bf16_rne(float f) {
    unsigned u = __float_as_uint(f);
    unsigned r = u + 0x7fffu + ((u >> 16) & 1u);
    return (unsigned short)(r >> 16);
}

// numpy pairwise_sum of 64 fp32 squares (8-accumulator scheme) — bit-exact
// vs np.sum(a*a, axis=1) for a 64-long row.
template <int STRIDE>
__device__ __forceinline__ float np_sumsq64(const float* __restrict__ a) {
    float r[8];
#pragma unroll
    for (int j = 0; j < 8; ++j) { const float v = a[j * STRIDE]; r[j] = __fmul_rn(v, v); }
#pragma unroll
    for (int i = 8; i < 64; i += 8)
#pragma unroll
        for (int j = 0; j < 8; ++j) {
            const float v = a[(i + j) * STRIDE];
            r[j] = __fadd_rn(r[j], __fmul_rn(v, v));
        }
    return __fadd_rn(
        __fadd_rn(__fadd_rn(r[0], r[1]), __fadd_rn(r[2], r[3])),
        __fadd_rn(__fadd_rn(r[4], r[5]), __fadd_rn(r[6], r[7])));
}

__global__ void vq_zero(float* __restrict__ out) { out[LOSS_OFF] = 0.0f; }

// Prep: bf16 codebook -> ws, Bs (numpy pairwise) -> ws, zero loss slot.
__global__ void vq_prep(const float* __restrict__ cb, unsigned short* __restrict__ wsb,
                        float* __restrict__ wsB, float* __restrict__ out) {
    const int gid = blockIdx.x * 256 + threadIdx.x;   // grid covers 512*64
    wsb[gid] = f32_to_bf16_rne(cb[gid]);
    if (gid < K_CODES) wsB[gid] = np_sumsq64<1>(cb + gid * C_DIM);
    if (gid == 0) out[LOSS_OFF] = 0.0f;
}

__global__ __launch_bounds__(256, 4) void vq_idx(const float* __restrict__ ze,
                                                 const float* __restrict__ cb,
                                                 float* __restrict__ out,
                                                 const unsigned short* __restrict__ wsb,
                                                 const float* __restrict__ wsB,
                                                 int use_ws)
{
    __shared__ unsigned short eh[CHUNK * EH_STRIDE];   // 18432 B bf16 code chunk
    __shared__ float  BsL[K_CODES];
    __shared__ float  As[TILE];
    __shared__ unsigned short cand[TILE * NSLOT];
    __shared__ int    cnt[TILE];
    __shared__ int    bestk[TILE];
    __shared__ double lred[4];

    const int tid  = threadIdx.x;          // 0..255 (4 waves)
    const int lane = tid & 63, w = tid >> 6;
    const int quad = lane >> 4, l15 = lane & 15;
    const int n0   = blockIdx.x * TILE;    // grid = 1024
    const int b    = n0 >> 12, hw0 = n0 & (HW - 1);
    const float* zebase = ze + b * CHW + hw0;

    if (use_ws) { for (int k = tid; k < K_CODES; k += 256) BsL[k] = wsB[k]; }
    else        { for (int k = tid; k < K_CODES; k += 256) BsL[k] = np_sumsq64<1>(cb + k * C_DIM); }
    if (tid < TILE) { As[tid] = np_sumsq64<HW>(zebase + tid); cnt[tid] = 0; }
    __syncthreads();

    // A fragments (bf16 RNE of x): A[m=lane&15][k=quad*8+j]; wave w owns
    // points w*32 .. w*32+31 (rt in {0,1}).
    short8 afr[2][2];
    float  A_pt[2][4], thr[2][4], runmin[2][4];
#pragma unroll
    for (int rt = 0; rt < 2; ++rt) {
        const int pt = w * 32 + rt * 16 + l15;
#pragma unroll
        for (int kc = 0; kc < 2; ++kc) {
            union { unsigned short s[8]; short8 v; } u;
#pragma unroll
            for (int j = 0; j < 8; ++j) {
                const int c = kc * 32 + quad * 8 + j;
                u.s[j] = f32_to_bf16_rne(zebase[c * HW + pt]);
            }
            afr[rt][kc] = u.v;
        }
#pragma unroll
        for (int r = 0; r < 4; ++r) {
            A_pt[rt][r]   = As[w * 32 + rt * 16 + quad * 4 + r];
            runmin[rt][r] = FLT_MAX;
        }
    }

    auto stage = [&](int ch) {   // 256 threads: one 64 B half-row each
        const int row = tid >> 1, half = tid & 1;
        uint4* dst = (uint4*)(eh + row * EH_STRIDE + half * 32);
        if (use_ws) {
            const uint4* src = (const uint4*)(wsb + (size_t)(ch * CHUNK + row) * C_DIM + half * 32);
#pragma unroll
            for (int i = 0; i < 4; ++i) dst[i] = src[i];
        } else {
            const float4* src = (const float4*)(cb + (size_t)(ch * CHUNK + row) * C_DIM + half * 32);
#pragma unroll
            for (int i = 0; i < 4; ++i) {
                const float4 f0 = src[2 * i], f1 = src[2 * i + 1];
                uint4 o;
                o.x = (unsigned)f32_to_bf16_rne(f0.x) | ((unsigned)f32_to_bf16_rne(f0.y) << 16);
                o.y = (unsigned)f32_to_bf16_rne(f0.z) | ((unsigned)f32_to_bf16_rne(f0.w) << 16);
                o.z = (unsigned)f32_to_bf16_rne(f1.x) | ((unsigned)f32_to_bf16_rne(f1.y) << 16);
                o.w = (unsigned)f32_to_bf16_rne(f1.z) | ((unsigned)f32_to_bf16_rne(f1.w) << 16);
                dst[i] = o;
            }
        }
    };

    // ---- pass 1: streaming approx-min over all 512 codes ----
    for (int ch = 0; ch < 4; ++ch) {
        __syncthreads(); stage(ch); __syncthreads();
        for (int tile = 0; tile < 8; ++tile) {
            const int cl = tile * 16 + l15;           // code = C col = lane&15
            const short8 b0 = *(const short8*)(eh + cl * EH_STRIDE + quad * 8);
            const short8 b1 = *(const short8*)(eh + cl * EH_STRIDE + 32 + quad * 8);
            const float bs = BsL[ch * CHUNK + cl];
#pragma unroll
            for (int rt = 0; rt < 2; ++rt) {
                f32x4 acc = {0.f, 0.f, 0.f, 0.f};
                acc = __builtin_amdgcn_mfma_f32_16x16x32_bf16(afr[rt][0], b0, acc, 0, 0, 0);
                acc = __builtin_amdgcn_mfma_f32_16x16x32_bf16(afr[rt][1], b1, acc, 0, 0, 0);
#pragma unroll
                for (int r = 0; r < 4; ++r) {
                    const float D = fmaf(-2.f, acc[r], __fadd_rn(A_pt[rt][r], bs));
                    runmin[rt][r] = fminf(runmin[rt][r], D);
                }
            }
        }
    }
    // cross-lane min over the 16 l15-lanes sharing each point; margin 3x the
    // rigorous bf16-vs-chain error bound.
#pragma unroll
    for (int rt = 0; rt < 2; ++rt)
#pragma unroll
        for (int r = 0; r < 4; ++r) {
            float v = runmin[rt][r];
#pragma unroll
            for (int m = 1; m < 16; m <<= 1) v = fminf(v, __shfl_xor(v, m, 64));
            thr[rt][r] = v + (4e-4f * sqrtf(A_pt[rt][r]) + 3e-4f);
        }

    // ---- pass 2: collect candidates under the global threshold ----
    for (int ch = 0; ch < 4; ++ch) {
        __syncthreads(); stage(ch); __syncthreads();
        for (int tile = 0; tile < 8; ++tile) {
            const int cl = tile * 16 + l15;
            const short8 b0 = *(const short8*)(eh + cl * EH_STRIDE + quad * 8);
            const short8 b1 = *(const short8*)(eh + cl * EH_STRIDE + 32 + quad * 8);
            const float bs = BsL[ch * CHUNK + cl];
#pragma unroll
            for (int rt = 0; rt < 2; ++rt) {
                f32x4 acc = {0.f, 0.f, 0.f, 0.f};
                acc = __builtin_amdgcn_mfma_f32_16x16x32_bf16(afr[rt][0], b0, acc, 0, 0, 0);
                acc = __builtin_amdgcn_mfma_f32_16x16x32_bf16(afr[rt][1], b1, acc, 0, 0, 0);
#pragma unroll
                for (int r = 0; r < 4; ++r) {
                    const float D = fmaf(-2.f, acc[r], __fadd_rn(A_pt[rt][r], bs));
                    if (D <= thr[rt][r]) {
                        const int pt = w * 32 + rt * 16 + quad * 4 + r;
                        const int p = atomicAdd(&cnt[pt], 1);
                        if (p < NSLOT) cand[pt * NSLOT + p] = (unsigned short)(ch * CHUNK + cl);
                    }
                }
            }
        }
    }
    __syncthreads();

    // ---- exact rescore (bit-exact numpy/BLAS chain), one thread per point ----
    if (tid < TILE) {
        const float Av = As[tid];
        const int c = cnt[tid];
        float bD = FLT_MAX; int bK = K_CODES;
        if (c <= NSLOT) {
            for (int i = 0; i < c; ++i) {
                const int k = cand[tid * NSLOT + i];
                const float* er = cb + k * C_DIM;
                float M = 0.f;
#pragma unroll
                for (int cc = 0; cc < 64; ++cc) M = fmaf(zebase[cc * HW + tid], er[cc], M);
                const float D = fmaf(-2.f, M, __fadd_rn(Av, BsL[k]));
                if (D < bD || (D == bD && k < bK)) { bD = D; bK = k; }
            }
        } else {  // overflow: exact full scan (ascending, strict <)
            for (int k = 0; k < K_CODES; ++k) {
                const float* er = cb + k * C_DIM;
                float M = 0.f;
#pragma unroll
                for (int cc = 0; cc < 64; ++cc) M = fmaf(zebase[cc * HW + tid], er[cc], M);
                const float D = fmaf(-2.f, M, __fadd_rn(Av, BsL[k]));
                if (D < bD) { bD = D; bK = k; }
            }
        }
        bestk[tid] = bK;
        out[IDX_OFF + n0 + tid] = (float)bK;
    }
    __syncthreads();

    // ---- epilogue: z_q_st (ref formula bitwise) + loss, float4 along hw ----
    double ls = 0.0;
#pragma unroll
    for (int it = 0; it < 8; ++it) {
        const int task = tid + 256 * it;          // 2048 tasks = 64 c x 32 quads
        const int c = task >> 5, q = task & 31;
        const float4 xz = *(const float4*)(zebase + c * HW + 4 * q);
        float o[4];
#pragma unroll
        for (int j = 0; j < 4; ++j) {
            const int k = bestk[4 * q + j];
            const float ev = cb[k * C_DIM + c];   // gather, L1/L2-hot
            const float xv = (j == 0) ? xz.x : (j == 1) ? xz.y : (j == 2) ? xz.z : xz.w;
            const float d = __fsub_rn(ev, xv);    // ref: z_q - z_e
            o[j] = __fadd_rn(xv, d);              // ref: z_e + (...)
            ls = fma((double)d, (double)d, ls);
        }
        *(float4*)(out + b * CHW + c * HW + hw0 + 4 * q) = make_float4(o[0], o[1], o[2], o[3]);
    }
#pragma unroll
    for (int off = 32; off > 0; off >>= 1) ls += __shfl_xor(ls, off, 64);
    if ((tid & 63) == 0) lred[w] = ls;
    __syncthreads();
    if (tid == 0)
        atomicAdd(out + LOSS_OFF,
                  (float)((lred[0] + lred[1] + lred[2] + lred[3]) * (1.25 / (double)ZQ_SIZE)));
}

extern "C" void kernel_launch(void* const* d_in, const int* in_sizes, int n_in,
                              void* d_out, int out_size, void* d_ws, size_t ws_size,
                              hipStream_t stream) {
    (void)in_sizes; (void)n_in; (void)out_size;
    const float* ze = (const float*)d_in[0];
    const float* cb = (const float*)d_in[1];
    float* out = (float*)d_out;
    const int use_ws = (ws_size >= WS_NEED) ? 1 : 0;
    unsigned short* wsb = (unsigned short*)d_ws;
    float* wsB = (float*)((char*)d_ws + WS_BF16);

    if (use_ws) vq_prep<<<(K_CODES * C_DIM) / 256, 256, 0, stream>>>(cb, wsb, wsB, out);
    else        vq_zero<<<1, 1, 0, stream>>>(out);
    vq_idx<<<NPTS / TILE, 256, 0, stream>>>(ze, cb, out, wsb, wsB, use_ws);
}